// Round 5
// baseline (4578.142 us; speedup 1.0000x reference)
//
#include <hip/hip_runtime.h>
#include <cstdint>
#include <cstddef>

#define HH  128      // H
#define KP1 65       // K+1
#define KD  32       // K_DIFF
#define NB  4096     // B

// thread (trow,tcol) owns rows trow*4..+3, cols {tcol*4..+3, 64+tcol*4..+3}
// split-column pair -> w_ch read bank start = 4*tcol -> 2-way alias only (free)

#define FMROW(AR, AS, W0, W1) do { \
    AR[0] = fmaf(AS, W0.x, AR[0]); AR[1] = fmaf(AS, W0.y, AR[1]); \
    AR[2] = fmaf(AS, W0.z, AR[2]); AR[3] = fmaf(AS, W0.w, AR[3]); \
    AR[4] = fmaf(AS, W1.x, AR[4]); AR[5] = fmaf(AS, W1.y, AR[5]); \
    AR[6] = fmaf(AS, W1.z, AR[6]); AR[7] = fmaf(AS, W1.w, AR[7]); } while (0)

// A-source rows R0..R3 (row base + chunk col offset), per-t w consumption:
// live regs per step: 16 (a) + 8 (w) instead of 16 + 32.
#define DO_CHUNK(R0, R1, R2, R3) do {                                   \
    _Pragma("unroll")                                                   \
    for (int kk4 = 0; kk4 < 8; ++kk4) {                                 \
        const int kb = kk4 * 4;                                         \
        float a0v[4], a1v[4], a2v[4], a3v[4];                           \
        *(float4*)a0v = *(const float4*)((R0) + kb);                    \
        *(float4*)a1v = *(const float4*)((R1) + kb);                    \
        *(float4*)a2v = *(const float4*)((R2) + kb);                    \
        *(float4*)a3v = *(const float4*)((R3) + kb);                    \
        _Pragma("unroll")                                               \
        for (int t = 0; t < 4; ++t) {                                   \
            float4 wAv = *(const float4*)&w_ch[kb + t][c0];             \
            float4 wBv = *(const float4*)&w_ch[kb + t][c1];             \
            FMROW(acc[0], a0v[t], wAv, wBv);                            \
            FMROW(acc[1], a1v[t], wAv, wBv);                            \
            FMROW(acc[2], a2v[t], wAv, wBv);                            \
            FMROW(acc[3], a3v[t], wAv, wBv);                            \
        }                                                               \
    }                                                                   \
} while (0)

#define LOADW(WPTR, KC) do {                                            \
    const float* wsrc = (WPTR) + (size_t)((KC) + wr) * HH + ws;         \
    wv0 = *(const float4*)(wsrc);      wv1 = *(const float4*)(wsrc + 4);\
    wv2 = *(const float4*)(wsrc + 8);  wv3 = *(const float4*)(wsrc + 12); } while (0)

#define STOREW() do {                                                   \
    *(float4*)&w_ch[wr][ws]      = wv0; *(float4*)&w_ch[wr][ws + 4]  = wv1; \
    *(float4*)&w_ch[wr][ws + 8]  = wv2; *(float4*)&w_ch[wr][ws + 12] = wv3; } while (0)

// ---------------------------------------------------------------------------
// Kernel A: fused gather + 2-layer node MLP. 64x128 tile, 256 thr, 4x8 micro.
// ---------------------------------------------------------------------------
__global__ __launch_bounds__(256, 2) void node_mlp_kernel(
    const float* __restrict__ user_text, const float* __restrict__ item_text,
    const int*   __restrict__ user_inds, const int*   __restrict__ item_inds,
    const float* __restrict__ user_emb,  const float* __restrict__ item_emb,
    const float* __restrict__ W1, const float* __restrict__ b1v,
    const float* __restrict__ W2, const float* __restrict__ b2v,
    float* __restrict__ nodes)
{
    __shared__ float a_ch[64][36];    // 32-wide K chunk, +4 pad
    __shared__ float w_ch[32][128];
    __shared__ float x1s[64][132];    // stage-1 output, +4 pad

    const int tid  = threadIdx.x;
    const int trow = tid >> 4;
    const int tcol = tid & 15;
    const int c0   = tcol * 4;
    const int c1   = 64 + tcol * 4;
    const int row0 = blockIdx.x * 64;

    // loader: 4 threads per row, 8 floats each
    const int lr  = tid >> 2;
    const int seg = (tid & 3) * 8;
    const int gr_l   = row0 + lr;
    const int side_l = gr_l / (NB * KP1);
    const int rem_l  = gr_l - side_l * (NB * KP1);
    const int k_l    = rem_l % KP1;
    const float* text_row = (side_l ? item_text : user_text) + (size_t)rem_l * HH;
    const int    ind_l    = (side_l ? item_inds : user_inds)[rem_l];
    const float* tab_l    = (side_l == 0) ? ((k_l < KD) ? item_emb : user_emb)
                                          : ((k_l < KD) ? user_emb : item_emb);
    const float* emb_row  = tab_l + (size_t)ind_l * HH;

    const int wr = tid >> 3;          // 0..31
    const int ws = (tid & 7) * 16;    // 0..112

#define LOADA1(KC) do {                                                  \
    const float* asrc = ((KC) + seg < HH) ? (text_row + (KC) + seg)      \
                                          : (emb_row + ((KC) + seg - HH));\
    av0 = *(const float4*)(asrc); av1 = *(const float4*)(asrc + 4); } while (0)

    float acc[4][8];
#pragma unroll
    for (int i = 0; i < 4; ++i)
#pragma unroll
        for (int j = 0; j < 8; ++j) acc[i][j] = 0.f;

    float4 av0, av1, wv0, wv1, wv2, wv3;
    LOADA1(0); LOADW(W1, 0);

    const float* ar0 = &a_ch[trow * 4 + 0][0];
    const float* ar1 = &a_ch[trow * 4 + 1][0];
    const float* ar2 = &a_ch[trow * 4 + 2][0];
    const float* ar3 = &a_ch[trow * 4 + 3][0];

    // ---------------- stage 1: K = 256 ----------------
    for (int kc = 0; kc < 2 * HH; kc += 32) {
        __syncthreads();               // prior chunk compute done
        *(float4*)&a_ch[lr][seg]     = av0;
        *(float4*)&a_ch[lr][seg + 4] = av1;
        STOREW();
        __syncthreads();
        if (kc + 32 < 2 * HH) { LOADA1(kc + 32); LOADW(W1, kc + 32); }
        else                  { LOADW(W2, 0); }   // prefetch stage-2 chunk 0
        DO_CHUNK(ar0, ar1, ar2, ar3);
    }

    // bias + relu -> x1s
    {
        float4 b0 = *(const float4*)(b1v + c0);
        float4 b1 = *(const float4*)(b1v + c1);
        const float bias[8] = {b0.x, b0.y, b0.z, b0.w, b1.x, b1.y, b1.z, b1.w};
#pragma unroll
        for (int i = 0; i < 4; ++i) {
            float tmp[8];
#pragma unroll
            for (int j = 0; j < 8; ++j) {
                tmp[j] = fmaxf(acc[i][j] + bias[j], 0.f);
                acc[i][j] = 0.f;
            }
            *(float4*)&x1s[trow * 4 + i][c0] = *(float4*)&tmp[0];
            *(float4*)&x1s[trow * 4 + i][c1] = *(float4*)&tmp[4];
        }
    }

    // ---------------- stage 2: K = 128 ----------------
    for (int kc = 0; kc < HH; kc += 32) {
        __syncthreads();               // x1s visible + prior w_ch reads done
        STOREW();
        __syncthreads();
        if (kc + 32 < HH) LOADW(W2, kc + 32);
        const float* xr0 = &x1s[trow * 4 + 0][kc];
        const float* xr1 = &x1s[trow * 4 + 1][kc];
        const float* xr2 = &x1s[trow * 4 + 2][kc];
        const float* xr3 = &x1s[trow * 4 + 3][kc];
        DO_CHUNK(xr0, xr1, xr2, xr3);
    }

    {
        float4 b0 = *(const float4*)(b2v + c0);
        float4 b1 = *(const float4*)(b2v + c1);
        const float bias[8] = {b0.x, b0.y, b0.z, b0.w, b1.x, b1.y, b1.z, b1.w};
#pragma unroll
        for (int i = 0; i < 4; ++i) {
            const int gr = row0 + trow * 4 + i;
            float tmp[8];
#pragma unroll
            for (int j = 0; j < 8; ++j) tmp[j] = fmaxf(acc[i][j] + bias[j], 0.f);
            float* dst = nodes + (size_t)gr * HH;
            *(float4*)(dst + c0) = *(float4*)&tmp[0];
            *(float4*)(dst + c1) = *(float4*)&tmp[4];
        }
    }
#undef LOADA1
}

// ---------------------------------------------------------------------------
// Kernel B: attention per (side, b). 8192 blocks, 256 threads.
// feat=[this|rel|ne]; this-block is rank-1 (v0); rel/ne blocks = 8 flat chunks.
// ---------------------------------------------------------------------------
__global__ __launch_bounds__(256, 2) void att_kernel(
    const float* __restrict__ nodes,
    const float* __restrict__ user_diff_rel, const float* __restrict__ item_diff_rel,
    const float* __restrict__ A1, const float* __restrict__ ab1,
    const float* __restrict__ A2, const float* __restrict__ ab2,
    float* __restrict__ ufeat)
{
    __shared__ float ne_s[64][132];
    __shared__ float rel_s[32][132];
    __shared__ float w_ch[32][128];
    __shared__ float this_s[128];
    __shared__ float v0p[2][128];
    __shared__ float att_s[64];

    const int tid  = threadIdx.x;
    const int bid  = blockIdx.x;
    const int side = bid >> 12;
    const int b    = bid & (NB - 1);

    const float* nbase = nodes + (size_t)((side * NB + b) * KP1) * HH;
    const float* drel  = (side ? item_diff_rel : user_diff_rel) + (size_t)b * KD * HH;

    const int trow = tid >> 4;
    const int tcol = tid & 15;
    const int c0   = tcol * 4;
    const int c1   = 64 + tcol * 4;
    const int wr   = tid >> 3;
    const int ws   = (tid & 7) * 16;

    // ---- stage ne / rel / this into LDS ----
    if (tid < HH) this_s[tid] = nbase[64 * HH + tid];
    for (int idx = tid; idx < 64 * 32; idx += 256) {
        const int r = idx >> 5, c = (idx & 31) * 4;
        *(float4*)&ne_s[r][c] = *(const float4*)(nbase + r * HH + c);
    }
    for (int idx = tid; idx < 32 * 32; idx += 256) {
        const int r = idx >> 5, c = (idx & 31) * 4;
        *(float4*)&rel_s[r][c] = *(const float4*)(drel + r * HH + c);
    }

    float4 wv0, wv1, wv2, wv3;
    LOADW(A1 + (size_t)HH * HH, 0);    // chunk 0 of the flattened 8-chunk loop
    __syncthreads();                   // staging visible

    // ---- rank-1 "this" block: v0 partials, all 256 threads ----
    {
        const int vcol  = tid & 127;
        const int vhalf = tid >> 7;
        float s = 0.f;
        const float* ap = A1 + (size_t)(vhalf * 64) * HH + vcol;
#pragma unroll 8
        for (int d = 0; d < 64; ++d)
            s = fmaf(this_s[vhalf * 64 + d], ap[(size_t)d * HH], s);
        v0p[vhalf][vcol] = s;
    }

    float acc[4][8];
    const float* relbase = &rel_s[trow * 4][0];
    const float* nebase  = &ne_s[trow * 4][0];

    // ---- 8 flat chunks: cc 0..3 = rel-block (A1 rows 128..255),
    //                     cc 4..7 = ne-block  (A1 rows 256..383) ----
    for (int cc = 0; cc < 8; ++cc) {
        __syncthreads();               // v0p visible (cc=0) / prior compute done
        STOREW();
        __syncthreads();
        if (cc < 7) LOADW(A1 + (size_t)(HH + (cc + 1) * 32) * HH, 0);
        if (cc == 0) {                 // init acc = ab1 + this@A1[0:128]
            float4 p0A = *(const float4*)&v0p[0][c0];
            float4 p0B = *(const float4*)&v0p[0][c1];
            float4 p1A = *(const float4*)&v0p[1][c0];
            float4 p1B = *(const float4*)&v0p[1][c1];
            float4 bA  = *(const float4*)(ab1 + c0);
            float4 bB  = *(const float4*)(ab1 + c1);
            const float base8[8] = {
                p0A.x + p1A.x + bA.x, p0A.y + p1A.y + bA.y,
                p0A.z + p1A.z + bA.z, p0A.w + p1A.w + bA.w,
                p0B.x + p1B.x + bB.x, p0B.y + p1B.y + bB.y,
                p0B.z + p1B.z + bB.z, p0B.w + p1B.w + bB.w };
#pragma unroll
            for (int i = 0; i < 4; ++i)
#pragma unroll
                for (int j = 0; j < 8; ++j) acc[i][j] = base8[j];
        }
        const int  kcp  = (cc & 3) * 32;           // col offset within the block
        const bool isP0 = (cc < 4);
        // wave-uniform row-source select: rows all <KD or all >=KD per thread
        const float* base = (isP0 && trow < 8) ? (relbase + kcp) : (nebase + kcp);
        const bool mulThis = isP0 && (trow >= 8);
#pragma unroll
        for (int kk4 = 0; kk4 < 8; ++kk4) {
            const int kb = kk4 * 4;
            float a0v[4], a1v[4], a2v[4], a3v[4];
            *(float4*)a0v = *(const float4*)(base + 0 * 132 + kb);
            *(float4*)a1v = *(const float4*)(base + 1 * 132 + kb);
            *(float4*)a2v = *(const float4*)(base + 2 * 132 + kb);
            *(float4*)a3v = *(const float4*)(base + 3 * 132 + kb);
            if (mulThis) {
                float th[4];
                *(float4*)th = *(const float4*)&this_s[kcp + kb];
#pragma unroll
                for (int t = 0; t < 4; ++t) {
                    a0v[t] *= th[t]; a1v[t] *= th[t];
                    a2v[t] *= th[t]; a3v[t] *= th[t];
                }
            }
#pragma unroll
            for (int t = 0; t < 4; ++t) {
                float4 wAv = *(const float4*)&w_ch[kb + t][c0];
                float4 wBv = *(const float4*)&w_ch[kb + t][c1];
                FMROW(acc[0], a0v[t], wAv, wBv);
                FMROW(acc[1], a1v[t], wAv, wBv);
                FMROW(acc[2], a2v[t], wAv, wBv);
                FMROW(acc[3], a3v[t], wAv, wBv);
            }
        }
    }

    // h = relu(acc); s[r] = relu(h . A2 + ab2)
    float w2v[8];
    {
        float4 a0 = *(const float4*)(A2 + c0);
        float4 a1 = *(const float4*)(A2 + c1);
        w2v[0] = a0.x; w2v[1] = a0.y; w2v[2] = a0.z; w2v[3] = a0.w;
        w2v[4] = a1.x; w2v[5] = a1.y; w2v[6] = a1.z; w2v[7] = a1.w;
    }
    const float bb2 = ab2[0];
    float p[4];
#pragma unroll
    for (int i = 0; i < 4; ++i) {
        p[i] = 0.f;
#pragma unroll
        for (int j = 0; j < 8; ++j) p[i] = fmaf(fmaxf(acc[i][j], 0.f), w2v[j], p[i]);
    }
#pragma unroll
    for (int m = 1; m < 16; m <<= 1)
#pragma unroll
        for (int i = 0; i < 4; ++i) p[i] += __shfl_xor(p[i], m);
    if (tcol == 0) {
#pragma unroll
        for (int i = 0; i < 4; ++i) att_s[trow * 4 + i] = fmaxf(p[i] + bb2, 0.f);
    }
    __syncthreads();

    // softmax over 64 (one wave)
    if (tid < 64) {
        const float v = att_s[tid];
        float m = v;
#pragma unroll
        for (int off = 1; off < 64; off <<= 1) m = fmaxf(m, __shfl_xor(m, off));
        const float e = expf(v - m);
        float ssum = e;
#pragma unroll
        for (int off = 1; off < 64; off <<= 1) ssum += __shfl_xor(ssum, off);
        att_s[tid] = e / ssum;
    }
    __syncthreads();

    if (tid < HH) {
        float aggv = 0.f;
#pragma unroll
        for (int k = 0; k < 64; ++k) aggv = fmaf(att_s[k], ne_s[k][tid], aggv);
        float* orow = ufeat + (size_t)(side * NB + b) * 256;
        orow[tid]      = this_s[tid];
        orow[HH + tid] = aggv;
    }
}

// ---------------------------------------------------------------------------
// Kernel C: transform. rows = 2*B; in stride 256; two layers.
// ---------------------------------------------------------------------------
__global__ __launch_bounds__(256, 2) void transform_kernel(
    const float* __restrict__ ufeat,
    const float* __restrict__ W1, const float* __restrict__ b1v,
    const float* __restrict__ W2, const float* __restrict__ b2v,
    float* __restrict__ out)
{
    __shared__ float a_ch[64][36];
    __shared__ float w_ch[32][128];
    __shared__ float x1s[64][132];

    const int tid  = threadIdx.x;
    const int trow = tid >> 4;
    const int tcol = tid & 15;
    const int c0   = tcol * 4;
    const int c1   = 64 + tcol * 4;
    const int row0 = blockIdx.x * 64;

    const int lr  = tid >> 2;
    const int seg = (tid & 3) * 8;
    const float* in_row = ufeat + (size_t)(row0 + lr) * 256;

    const int wr = tid >> 3;
    const int ws = (tid & 7) * 16;

    float acc[4][8];
#pragma unroll
    for (int i = 0; i < 4; ++i)
#pragma unroll
        for (int j = 0; j < 8; ++j) acc[i][j] = 0.f;

    float4 av0, av1, wv0, wv1, wv2, wv3;
    av0 = *(const float4*)(in_row + seg);
    av1 = *(const float4*)(in_row + seg + 4);
    LOADW(W1, 0);

    const float* ar0 = &a_ch[trow * 4 + 0][0];
    const float* ar1 = &a_ch[trow * 4 + 1][0];
    const float* ar2 = &a_ch[trow * 4 + 2][0];
    const float* ar3 = &a_ch[trow * 4 + 3][0];

    for (int kc = 0; kc < 256; kc += 32) {
        __syncthreads();
        *(float4*)&a_ch[lr][seg]     = av0;
        *(float4*)&a_ch[lr][seg + 4] = av1;
        STOREW();
        __syncthreads();
        if (kc + 32 < 256) {
            av0 = *(const float4*)(in_row + kc + 32 + seg);
            av1 = *(const float4*)(in_row + kc + 32 + seg + 4);
            LOADW(W1, kc + 32);
        } else {
            LOADW(W2, 0);
        }
        DO_CHUNK(ar0, ar1, ar2, ar3);
    }

    {
        float4 b0 = *(const float4*)(b1v + c0);
        float4 b1 = *(const float4*)(b1v + c1);
        const float bias[8] = {b0.x, b0.y, b0.z, b0.w, b1.x, b1.y, b1.z, b1.w};
#pragma unroll
        for (int i = 0; i < 4; ++i) {
            float tmp[8];
#pragma unroll
            for (int j = 0; j < 8; ++j) {
                tmp[j] = fmaxf(acc[i][j] + bias[j], 0.f);
                acc[i][j] = 0.f;
            }
            *(float4*)&x1s[trow * 4 + i][c0] = *(float4*)&tmp[0];
            *(float4*)&x1s[trow * 4 + i][c1] = *(float4*)&tmp[4];
        }
    }

    for (int kc = 0; kc < HH; kc += 32) {
        __syncthreads();
        STOREW();
        __syncthreads();
        if (kc + 32 < HH) LOADW(W2, kc + 32);
        const float* xr0 = &x1s[trow * 4 + 0][kc];
        const float* xr1 = &x1s[trow * 4 + 1][kc];
        const float* xr2 = &x1s[trow * 4 + 2][kc];
        const float* xr3 = &x1s[trow * 4 + 3][kc];
        DO_CHUNK(xr0, xr1, xr2, xr3);
    }

    {
        float4 b0 = *(const float4*)(b2v + c0);
        float4 b1 = *(const float4*)(b2v + c1);
        const float bias[8] = {b0.x, b0.y, b0.z, b0.w, b1.x, b1.y, b1.z, b1.w};
#pragma unroll
        for (int i = 0; i < 4; ++i) {
            const int gr = row0 + trow * 4 + i;
            float tmp[8];
#pragma unroll
            for (int j = 0; j < 8; ++j) tmp[j] = fmaxf(acc[i][j] + bias[j], 0.f);
            float* dst = out + (size_t)gr * HH;
            *(float4*)(dst + c0) = *(float4*)&tmp[0];
            *(float4*)(dst + c1) = *(float4*)&tmp[4];
        }
    }
}

// ---------------------------------------------------------------------------
extern "C" void kernel_launch(void* const* d_in, const int* in_sizes, int n_in,
                              void* d_out, int out_size, void* d_ws, size_t ws_size,
                              hipStream_t stream)
{
    (void)in_sizes; (void)n_in; (void)out_size; (void)ws_size;

    const float* user_text     = (const float*)d_in[0];
    const float* item_text     = (const float*)d_in[1];
    const float* user_diff_rel = (const float*)d_in[2];
    const float* item_diff_rel = (const float*)d_in[3];
    const int*   user_inds     = (const int*)d_in[4];
    const int*   item_inds     = (const int*)d_in[5];
    const float* user_emb      = (const float*)d_in[6];
    const float* item_emb      = (const float*)d_in[7];
    const float* ne_W1         = (const float*)d_in[8];
    const float* ne_b1         = (const float*)d_in[9];
    const float* ne_W2         = (const float*)d_in[10];
    const float* ne_b2         = (const float*)d_in[11];
    const float* att_W1        = (const float*)d_in[12];
    const float* att_b1        = (const float*)d_in[13];
    const float* att_W2        = (const float*)d_in[14];
    const float* att_b2        = (const float*)d_in[15];
    const float* tr_W1         = (const float*)d_in[16];
    const float* tr_b1         = (const float*)d_in[17];
    const float* tr_W2         = (const float*)d_in[18];
    const float* tr_b2         = (const float*)d_in[19];

    float* nodes = (float*)d_ws;                                  // 2*B*65*128 f32
    float* ufeat = nodes + (size_t)2 * NB * KP1 * HH;             // 2*B*256 f32
    float* out   = (float*)d_out;                                 // 2*B*128 f32

    const int rowsA = 2 * NB * KP1;   // 532480, divisible by 64
    hipLaunchKernelGGL(node_mlp_kernel, dim3(rowsA / 64), dim3(256), 0, stream,
                       user_text, item_text, user_inds, item_inds,
                       user_emb, item_emb, ne_W1, ne_b1, ne_W2, ne_b2, nodes);

    hipLaunchKernelGGL(att_kernel, dim3(2 * NB), dim3(256), 0, stream,
                       nodes, user_diff_rel, item_diff_rel,
                       att_W1, att_b1, att_W2, att_b2, ufeat);

    hipLaunchKernelGGL(transform_kernel, dim3(2 * NB / 64), dim3(256), 0, stream,
                       ufeat, tr_W1, tr_b1, tr_W2, tr_b2, out);
}